// Round 10
// baseline (122.447 us; speedup 1.0000x reference)
//
#include <hip/hip_runtime.h>

// YOLOv1 head post-process — R10: ONE WAVE = ONE BATCH. 64-thread blocks,
// grid = 1024. R8->R9 showed adding co-resident blocks doesn't help: every
// block has the same barriered phase chain (load->softmax->adj->NMS->write),
// so they stall in lockstep. Here each batch is a single straight-line wave
// program: __syncthreads on a 1-wave block is a near-free waitcnt+barrier,
// softmax no longer blocks sibling waves, stores from the 4 waves/CU start
// independently. Per-batch math identical to R9 (passed):
//  * contested-set NMS: candidate overlapping no OTHER candidate is kept;
//    NMS(cand) = (cand\S) ∪ NMS(S); usually no rank/scan at all.
//  * adjacency by wave-ballot over union-candidate rows only (ctz bit-walk).
//  * SoA boxes; box coords held in registers from decode.
// Softmax float-op sequence bit-identical to R1-R9 (decision safety).
// Equivalence notes (carried, R1-R5/R8/R9 passed):
//  * score < SCORE_T boxes only suppress even-lower-sorted boxes (all zeroed
//    by final score filter) -> NMS over score>=SCORE_T candidates exact.
//  * candidate => conf*(1/sum) >= SCORE_T in float (monotone) -> union mask
//    covers every possible candidate; non-union adj rows never read.
//  * contested restriction exact (IoU symmetric).
//  * rank tie-break = box index ascending = jnp stable argsort(-scores).
//  * K>64 (prob ~0) falls back to ballot-greedy (exact).

namespace {
constexpr int kS    = 7;
constexpr int kC    = 20;
constexpr int kFeat = 30;             // C + 5*BBOX
constexpr int kN    = 98;             // S*S*2 boxes
constexpr int kRows = kN * kC;        // 1960
constexpr int kOutF = kRows * 6;      // 11760 floats per batch
constexpr float kIouT   = 0.5f;
constexpr float kScoreT = 0.05f;
}

__device__ __forceinline__ float iou_f(float ax1, float ay1, float ax2, float ay2,
                                       float bx1, float by1, float bx2, float by2) {
#pragma clang fp contract(off)
    float aa = fmaxf(ax2 - ax1, 0.f) * fmaxf(ay2 - ay1, 0.f);
    float ab = fmaxf(bx2 - bx1, 0.f) * fmaxf(by2 - by1, 0.f);
    float ix1 = fmaxf(ax1, bx1);
    float iy1 = fmaxf(ay1, by1);
    float ix2 = fminf(ax2, bx2);
    float iy2 = fminf(ay2, by2);
    float inter = fmaxf(ix2 - ix1, 0.f) * fmaxf(iy2 - iy1, 0.f);
    float uni = aa + ab - inter;
    return inter / fmaxf(uni, 1e-9f);
}

__device__ __forceinline__ unsigned long long shfl64(unsigned long long v, int src) {
    unsigned lo = (unsigned)__shfl((int)(unsigned)(v & 0xffffffffull), src);
    unsigned hi = (unsigned)__shfl((int)(unsigned)(v >> 32), src);
    return ((unsigned long long)hi << 32) | lo;
}

__global__ __launch_bounds__(64) void yolo_head_kernel(const float* __restrict__ x,
                                                       float* __restrict__ out) {
    __shared__ float xs[kS * kS * kFeat];                   // 1470 input floats
    __shared__ float scT[kRows];                            // scores [c][n]
    __shared__ float maxp[kS * kS];                         // 1/sum per cell
    __shared__ float x1s[kN], y1s[kN], x2s[kN], y2s[kN];    // SoA boxes
    __shared__ unsigned long long adjLo[kN], adjHi[kN];     // IoU>T rows (union only)
    __shared__ float csc[kN];                               // cand scores
    __shared__ unsigned short cid[kN];                      // cand box idx
    __shared__ unsigned short rnk[64], rid[64];             // rank maps
    __shared__ unsigned km[kC][4];                          // keep mask per class

    const int b    = blockIdx.x;
    const int lane = threadIdx.x;                           // 0..63 (one wave)
    const float* xb = x + (size_t)b * (kS * kS * kFeat);

    {   // load 1470 floats = 735 float2 (batch stride 5880 B, 8B-aligned)
        const float2* s = reinterpret_cast<const float2*>(xb);
        float2* d = reinterpret_cast<float2*>(xs);
        for (int e = lane; e < (kS * kS * kFeat) / 2; e += 64) d[e] = s[e];
    }
    __syncthreads();   // 1-wave block: waitcnt + cheap barrier

    // ---- phase 1: decode boxes (kept in registers too) + softmax ----
    float aX1, aY1, aX2, aY2;                 // box `lane`
    float bX1 = 0.f, bY1 = 0.f, bX2 = 0.f, bY2 = 0.f;   // box `lane+64`
    {
#pragma clang fp contract(off)
        {   // box n = lane (all 64 lanes; n < 98)
            const int n = lane;
            const int cell = n >> 1, k = n & 1;
            const int gi = cell / kS, gj = cell % kS;   // gy=gi, gx=gj
            const float* p = &xs[cell * kFeat + kC + 4 * k];
            float cx = (p[0] + (float)gj) / 7.0f;
            float cy = (p[1] + (float)gi) / 7.0f;
            float w = p[2], h = p[3];
            aX1 = fminf(fmaxf(cx - w * 0.5f, 0.f), 1.f) * 448.f;
            aY1 = fminf(fmaxf(cy - h * 0.5f, 0.f), 1.f) * 448.f;
            aX2 = fminf(fmaxf(cx + w * 0.5f, 0.f), 1.f) * 448.f;
            aY2 = fminf(fmaxf(cy + h * 0.5f, 0.f), 1.f) * 448.f;
            x1s[n] = aX1; y1s[n] = aY1; x2s[n] = aX2; y2s[n] = aY2;
        }
        if (lane < kN - 64) {   // box n = lane + 64 (lanes 0..33)
            const int n = lane + 64;
            const int cell = n >> 1, k = n & 1;
            const int gi = cell / kS, gj = cell % kS;
            const float* p = &xs[cell * kFeat + kC + 4 * k];
            float cx = (p[0] + (float)gj) / 7.0f;
            float cy = (p[1] + (float)gi) / 7.0f;
            float w = p[2], h = p[3];
            bX1 = fminf(fmaxf(cx - w * 0.5f, 0.f), 1.f) * 448.f;
            bY1 = fminf(fmaxf(cy - h * 0.5f, 0.f), 1.f) * 448.f;
            bX2 = fminf(fmaxf(cx + w * 0.5f, 0.f), 1.f) * 448.f;
            bY2 = fminf(fmaxf(cy + h * 0.5f, 0.f), 1.f) * 448.f;
            x1s[n] = bX1; y1s[n] = bY1; x2s[n] = bX2; y2s[n] = bY2;
        }
        if (lane < kS * kS) {   // softmax, op order bit-identical to R1-R9
            const int cell = lane;
            const float* p = &xs[cell * kFeat];
            float mx = p[0];
            for (int c = 1; c < kC; ++c) mx = fmaxf(mx, p[c]);
            float e[kC];
            float sum = 0.f;
            for (int c = 0; c < kC; ++c) { e[c] = expf(p[c] - mx); sum += e[c]; }
            const float conf0 = p[28], conf1 = p[29];
            for (int c = 0; c < kC; ++c) {
                float pr = e[c] / sum;
                scT[c * kN + 2 * cell]     = pr * conf0;
                scT[c * kN + 2 * cell + 1] = pr * conf1;
            }
            maxp[cell] = 1.0f / sum;    // exp(0)=1 is the exact max of e[]
        }
    }
    __syncthreads();

    const int nB = (lane < kN - 64) ? lane + 64 : 0;   // valid dummy for lane>=34

    // ---- phase 2: union mask + ballot adjacency (ctz walk over union bits) ----
    {
        const int cA = lane >> 1, kA = lane & 1;
        const bool uA = xs[cA * kFeat + 28 + kA] * maxp[cA] >= kScoreT;
        bool uB = false;
        if (lane < kN - 64) {
            const int cB = nB >> 1, kB = nB & 1;
            uB = xs[cB * kFeat + 28 + kB] * maxp[cB] >= kScoreT;
        }
        const unsigned long long ULo = __ballot(uA);
        const unsigned long long UHi = __ballot(uB);
        unsigned long long m = ULo;
        while (m) {
            const int i = __builtin_ctzll(m);
            m &= m - 1;
            const float iX1 = x1s[i], iY1 = y1s[i], iX2 = x2s[i], iY2 = y2s[i];
            const bool oA = iou_f(iX1, iY1, iX2, iY2, aX1, aY1, aX2, aY2) > kIouT;
            const bool oB = (lane < kN - 64) &&
                            iou_f(iX1, iY1, iX2, iY2, bX1, bY1, bX2, bY2) > kIouT;
            const unsigned long long rLo = __ballot(oA);
            const unsigned long long rHi = __ballot(oB);
            if (lane == 0) { adjLo[i] = rLo; adjHi[i] = rHi; }
        }
        m = UHi;
        while (m) {
            const int i = 64 + __builtin_ctzll(m);
            m &= m - 1;
            const float iX1 = x1s[i], iY1 = y1s[i], iX2 = x2s[i], iY2 = y2s[i];
            const bool oA = iou_f(iX1, iY1, iX2, iY2, aX1, aY1, aX2, aY2) > kIouT;
            const bool oB = (lane < kN - 64) &&
                            iou_f(iX1, iY1, iX2, iY2, bX1, bY1, bX2, bY2) > kIouT;
            const unsigned long long rLo = __ballot(oA);
            const unsigned long long rHi = __ballot(oB);
            if (lane == 0) { adjLo[i] = rLo; adjHi[i] = rHi; }
        }
    }
    __syncthreads();

    // ---- phase 3: per-class NMS with contested-set restriction (20 classes) ----
    {
        const unsigned long long rowLoA = adjLo[lane], rowHiA = adjHi[lane];
        const unsigned long long rowLoB = adjLo[nB],   rowHiB = adjHi[nB];
        const unsigned long long selfA  = 1ull << lane;  // A self in Lo; B self in Hi bit `lane`
        const unsigned long long lt     = (1ull << lane) - 1ull;
        for (int c = 0; c < kC; ++c) {
            const float s0 = scT[c * kN + lane];
            const bool  c0 = (s0 >= kScoreT);
            float s1 = 0.f;
            bool  c1 = false;
            if (lane < kN - 64) { s1 = scT[c * kN + 64 + lane]; c1 = (s1 >= kScoreT); }
            const unsigned long long candLo = __ballot(c0);
            const unsigned long long candHi = __ballot(c1);
            const int K = __popcll(candLo) + __popcll(candHi);

            // contested = candidate overlapping another candidate (cand ⊆ union ⇒ rows valid)
            const bool t0 = c0 && ((((rowLoA & candLo) & ~selfA) | (rowHiA & candHi)) != 0ull);
            const bool t1 = c1 && (((rowLoB & candLo) | ((rowHiB & candHi) & ~selfA)) != 0ull);
            const unsigned long long conLo = __ballot(t0);
            const unsigned long long conHi = __ballot(t1);

            unsigned long long keepLo, keepHi;
            if ((conLo | conHi) == 0ull) {
                keepLo = candLo; keepHi = candHi;          // nothing can suppress
            } else if (K <= 64) {
                // rank + scan over the contested set S only (KS <= 64)
                const int KS0 = __popcll(conLo);
                const int KS  = KS0 + __popcll(conHi);
                int q0 = 0, q1 = 0;
                if (t0) { q0 = __popcll(conLo & lt);       csc[q0] = s0; cid[q0] = (unsigned short)lane; }
                if (t1) { q1 = KS0 + __popcll(conHi & lt); csc[q1] = s1; cid[q1] = (unsigned short)(lane + 64); }
                __builtin_amdgcn_wave_barrier();
                const bool  act = (lane < KS);
                const float sp  = act ? csc[lane] : 0.f;
                int rp = 0;
                for (int q = 0; q < KS; ++q) {
                    const float sq = csc[q];               // broadcast read
                    rp += ((sq > sp) || ((sq == sp) && (q < lane))) ? 1 : 0;
                }
                if (act) { rnk[lane] = (unsigned short)rp; rid[rp] = cid[lane]; }
                __builtin_amdgcn_wave_barrier();
                const int myb = act ? (int)rid[lane] : 0;
                const unsigned long long rLo = adjLo[myb];
                const unsigned long long rHi = adjHi[myb];
                unsigned long long supLo = 0, supHi = 0, keepM = 0;
                for (int r = 0; r < KS; ++r) {
                    const int bi = __shfl(myb, r);         // indep of sup chain
                    const unsigned long long qLo = shfl64(rLo, r);
                    const unsigned long long qHi = shfl64(rHi, r);
                    const unsigned long long word = (bi & 64) ? supHi : supLo;
                    const unsigned long long bit  = (word >> (bi & 63)) & 1ull;
                    const unsigned long long take = bit - 1ull;  // ~0 if alive
                    keepM |= (1ull << r) & take;
                    supLo |= qLo & take;
                    supHi |= qHi & take;
                }
                const bool k0 = t0 && ((keepM >> rnk[q0]) & 1ull);
                const bool k1 = t1 && ((keepM >> rnk[q1]) & 1ull);
                keepLo = (candLo & ~conLo) | __ballot(k0);
                keepHi = (candHi & ~conHi) | __ballot(k1);
            } else {
                // fallback (K>64, prob ~0): ballot-greedy over all candidates
                const int K0 = __popcll(candLo);
                int p0 = 0, p1 = 0;
                if (c0) { p0 = __popcll(candLo & lt);      csc[p0] = s0; cid[p0] = (unsigned short)lane; }
                if (c1) { p1 = K0 + __popcll(candHi & lt); csc[p1] = s1; cid[p1] = (unsigned short)(lane + 64); }
                __builtin_amdgcn_wave_barrier();
                bool al0 = c0, al1 = c1, k0 = false, k1 = false;
                for (;;) {
                    float bs; int bp;
                    if (al0 && (!al1 || s0 >= s1)) { bs = s0; bp = p0; }
                    else if (al1)                  { bs = s1; bp = p1; }
                    else                           { bs = -1e30f; bp = 1 << 20; }
                    for (int off = 32; off; off >>= 1) {
                        const float os = __shfl_xor(bs, off);
                        const int   op = __shfl_xor(bp, off);
                        if (os > bs || (os == bs && op < bp)) { bs = os; bp = op; }
                    }
                    if (bp >= (1 << 20)) break;
                    const int bi = cid[bp];                // wave-uniform
                    const float kx1 = x1s[bi], ky1 = y1s[bi], kx2 = x2s[bi], ky2 = y2s[bi];
                    if (bp == p0 && al0) { k0 = true; al0 = false; }
                    if (bp == p1 && al1) { k1 = true; al1 = false; }
                    if (al0 && iou_f(kx1, ky1, kx2, ky2, aX1, aY1, aX2, aY2) > kIouT) al0 = false;
                    if (al1 && iou_f(kx1, ky1, kx2, ky2, bX1, bY1, bX2, bY2) > kIouT) al1 = false;
                }
                keepLo = __ballot(k0);
                keepHi = __ballot(k1);
            }
            if (lane == 0) {
                km[c][0] = (unsigned)keepLo;
                km[c][1] = (unsigned)(keepLo >> 32);
                km[c][2] = (unsigned)keepHi;
                km[c][3] = (unsigned)(keepHi >> 32);
            }
        }
    }
    __syncthreads();

    // ---- phase 4: writer — j emits rows 2j,2j+1 (same n) as 3 float4 ----
    for (int j = lane; j < kRows / 2; j += 64) {
        const int n = j / 10;                 // rows 2j,2j+1 share n
        const int c0i = 2 * (j % 10);
        const int c1i = c0i + 1;
        const float sA = scT[c0i * kN + n];
        const float sB = scT[c1i * kN + n];
        const float bbx = x1s[n], bby = y1s[n], bbz = x2s[n], bbw = y2s[n];
        const float mA = ((km[c0i][n >> 5] >> (n & 31)) & 1u) ? 1.f : 0.f;
        const float mB = ((km[c1i][n >> 5] >> (n & 31)) & 1u) ? 1.f : 0.f;
        float* ob = out + (size_t)b * kOutF + (size_t)12 * j;
        float4 q0, q1, q2;
        q0.x = mA * (float)c0i; q0.y = mA * bbx; q0.z = mA * bby; q0.w = mA * bbz;
        q1.x = mA * bbw;        q1.y = mA * sA;  q1.z = mB * (float)c1i; q1.w = mB * bbx;
        q2.x = mB * bby;        q2.y = mB * bbz; q2.z = mB * bbw;        q2.w = mB * sB;
        reinterpret_cast<float4*>(ob)[0] = q0;
        reinterpret_cast<float4*>(ob)[1] = q1;
        reinterpret_cast<float4*>(ob)[2] = q2;
    }
}

extern "C" void kernel_launch(void* const* d_in, const int* in_sizes, int n_in,
                              void* d_out, int out_size, void* d_ws, size_t ws_size,
                              hipStream_t stream) {
    const float* x = (const float*)d_in[0];
    float* out = (float*)d_out;
    const int B = in_sizes[0] / (kS * kS * kFeat);   // 1024
    hipLaunchKernelGGL(yolo_head_kernel, dim3(B), dim3(64), 0, stream, x, out);
}

// Round 11
// 102.864 us; speedup vs baseline: 1.1904x; 1.1904x over previous
//
#include <hip/hip_runtime.h>

// YOLOv1 head post-process — R11: R9 structure, but grid = 2*B. R10 proved the
// kernel is latency-bound on serial LDS/ballot round-trips (1 wave/SIMD ->
// 65us, VALUBusy 11%); R9's 16 waves/CU -> ~27us. Residency is grid-capped,
// so split each batch's 20 classes across TWO 256-thr blocks (half h does
// classes 10h..10h+9), duplicating prep (exact: classes independent, both
// halves compute identical boxes/adjacency). 2048 blocks -> 32 waves/CU
// (8/SIMD, max) = 2x stall interleave for ~1.4x VALU. Per-wave chain also
// halves (2-3 classes, half the softmax stores / writer rows).
// Per-batch math identical to R8-R10 (all passed):
//  * contested-set NMS: candidate overlapping no OTHER candidate is kept;
//    NMS(cand) = (cand\S) ∪ NMS(S); usually no rank/scan at all.
//  * adjacency by wave-ballot over union-candidate rows only.
//  * SoA boxes in LDS; per-wave score preload before the class loop.
// Softmax float-op sequence bit-identical to R1-R10 (decision safety; the
// skipped other-half pr writes don't alter our half's op sequence).
// Equivalence notes (carried):
//  * score < SCORE_T boxes only suppress even-lower-sorted boxes (all zeroed
//    by final score filter) -> NMS over score>=SCORE_T candidates exact.
//  * candidate => conf*(1/sum) >= SCORE_T in float (monotone) -> union mask
//    covers every candidate of every class; non-union adj rows never read.
//  * contested restriction exact (IoU symmetric).
//  * rank tie-break = box index ascending = jnp stable argsort(-scores).
//  * K>64 (prob ~0) falls back to ballot-greedy (exact).

namespace {
constexpr int kS    = 7;
constexpr int kC    = 20;
constexpr int kFeat = 30;             // C + 5*BBOX
constexpr int kN    = 98;             // S*S*2 boxes
constexpr int kHC   = 10;             // classes per block half
constexpr int kRows = kN * kC;        // 1960
constexpr int kOutF = kRows * 6;      // 11760 floats per batch
constexpr int kT    = 256;            // threads per block (4 waves)
constexpr float kIouT   = 0.5f;
constexpr float kScoreT = 0.05f;
}

__device__ __forceinline__ float iou_f(float ax1, float ay1, float ax2, float ay2,
                                       float bx1, float by1, float bx2, float by2) {
#pragma clang fp contract(off)
    float aa = fmaxf(ax2 - ax1, 0.f) * fmaxf(ay2 - ay1, 0.f);
    float ab = fmaxf(bx2 - bx1, 0.f) * fmaxf(by2 - by1, 0.f);
    float ix1 = fmaxf(ax1, bx1);
    float iy1 = fmaxf(ay1, by1);
    float ix2 = fminf(ax2, bx2);
    float iy2 = fminf(ay2, by2);
    float inter = fmaxf(ix2 - ix1, 0.f) * fmaxf(iy2 - iy1, 0.f);
    float uni = aa + ab - inter;
    return inter / fmaxf(uni, 1e-9f);
}

__device__ __forceinline__ unsigned long long shfl64(unsigned long long v, int src) {
    unsigned lo = (unsigned)__shfl((int)(unsigned)(v & 0xffffffffull), src);
    unsigned hi = (unsigned)__shfl((int)(unsigned)(v >> 32), src);
    return ((unsigned long long)hi << 32) | lo;
}

__global__ __launch_bounds__(kT, 8) void yolo_head_kernel(const float* __restrict__ x,
                                                          float* __restrict__ out) {
    __shared__ float xs[kS * kS * kFeat];                   // 1470 input floats
    __shared__ float scTh[kHC * kN];                        // our half's scores [lc][n]
    __shared__ float maxp[kS * kS];                         // 1/sum per cell
    __shared__ float x1s[kN], y1s[kN], x2s[kN], y2s[kN];    // SoA boxes
    __shared__ unsigned long long adjLo[kN], adjHi[kN];     // IoU>T rows (union only)
    __shared__ float csc[4][kN];                            // per-wave cand scores
    __shared__ unsigned short cid[4][kN];                   // per-wave cand box idx
    __shared__ unsigned short rnk[4][64];                   // S-pos -> rank
    __shared__ unsigned short rid[4][64];                   // rank -> box idx
    __shared__ unsigned km[kHC][4];                         // keep mask per local class

    const int b   = blockIdx.x >> 1;
    const int h   = blockIdx.x & 1;                         // class half
    const int tid = threadIdx.x;
    const float* xb = x + (size_t)b * (kS * kS * kFeat);

    for (int e = tid; e < (kS * kS * kFeat) / 2; e += kT)
        reinterpret_cast<float2*>(xs)[e] = reinterpret_cast<const float2*>(xb)[e];
    __syncthreads();

    // ---- phase 1: softmax (threads 0-48, bit-identical op order) + decode (64-161) ----
    if (tid < kS * kS) {
#pragma clang fp contract(off)
        const int cell = tid;
        const float* p = &xs[cell * kFeat];
        float mx = p[0];
        for (int c = 1; c < kC; ++c) mx = fmaxf(mx, p[c]);
        float e[kC];
        float sum = 0.f;
        for (int c = 0; c < kC; ++c) { e[c] = expf(p[c] - mx); sum += e[c]; }
        const float conf0 = p[28], conf1 = p[29];
        for (int lc = 0; lc < kHC; ++lc) {
            const int c = kHC * h + lc;
            float pr = e[c] / sum;                 // identical op as full version
            scTh[lc * kN + 2 * cell]     = pr * conf0;
            scTh[lc * kN + 2 * cell + 1] = pr * conf1;
        }
        maxp[cell] = 1.0f / sum;    // exp(0)=1 is the exact max of e[]
    } else if (tid >= 64 && tid < 64 + kN) {
#pragma clang fp contract(off)
        const int n = tid - 64;
        const int cell = n >> 1, k = n & 1;
        const int gi = cell / kS, gj = cell % kS;   // gy=gi, gx=gj
        const float* p = &xs[cell * kFeat + kC + 4 * k];
        float cx = (p[0] + (float)gj) / 7.0f;
        float cy = (p[1] + (float)gi) / 7.0f;
        float w = p[2], h2 = p[3];
        x1s[n] = fminf(fmaxf(cx - w * 0.5f, 0.f), 1.f) * 448.f;
        y1s[n] = fminf(fmaxf(cy - h2 * 0.5f, 0.f), 1.f) * 448.f;
        x2s[n] = fminf(fmaxf(cx + w * 0.5f, 0.f), 1.f) * 448.f;
        y2s[n] = fminf(fmaxf(cy + h2 * 0.5f, 0.f), 1.f) * 448.f;
    }
    __syncthreads();

    const int wv   = tid >> 6;
    const int lane = tid & 63;
    const int nB   = (lane < kN - 64) ? lane + 64 : 0;   // valid dummy for lane>=34

    // ---- phase 2: union mask + ballot-built adjacency (wave wv: rows wv, wv+4, ...) ----
    {
        const float aX1 = x1s[lane], aY1 = y1s[lane], aX2 = x2s[lane], aY2 = y2s[lane];
        const float bX1 = x1s[nB],  bY1 = y1s[nB],  bX2 = x2s[nB],  bY2 = y2s[nB];
        const int cA = lane >> 1, kA = lane & 1;
        const bool uA = xs[cA * kFeat + 28 + kA] * maxp[cA] >= kScoreT;
        bool uB = false;
        if (lane < kN - 64) {
            const int cB = nB >> 1, kB = nB & 1;
            uB = xs[cB * kFeat + 28 + kB] * maxp[cB] >= kScoreT;
        }
        const unsigned long long ULo = __ballot(uA);
        const unsigned long long UHi = __ballot(uB);
        for (int i = wv; i < kN; i += 4) {
            const bool inU = (i < 64) ? ((ULo >> i) & 1ull) : ((UHi >> (i - 64)) & 1ull);
            if (!inU) continue;
            const float iX1 = x1s[i], iY1 = y1s[i], iX2 = x2s[i], iY2 = y2s[i];
            const bool oA = iou_f(iX1, iY1, iX2, iY2, aX1, aY1, aX2, aY2) > kIouT;
            const bool oB = (lane < kN - 64) &&
                            iou_f(iX1, iY1, iX2, iY2, bX1, bY1, bX2, bY2) > kIouT;
            const unsigned long long rLo = __ballot(oA);
            const unsigned long long rHi = __ballot(oB);
            if (lane == 0) { adjLo[i] = rLo; adjHi[i] = rHi; }
        }
    }
    __syncthreads();

    // ---- phase 3: NMS over our half's classes; wave wv: lc = wv, wv+4, wv+8 ----
    {
        const unsigned long long rowLoA = adjLo[lane], rowHiA = adjHi[lane];
        const unsigned long long rowLoB = adjLo[nB],   rowHiB = adjHi[nB];
        const unsigned long long selfA  = 1ull << lane;  // A self in Lo; B self in Hi bit `lane`
        const unsigned long long lt     = (1ull << lane) - 1ull;
        const int ncl = (wv < 2) ? 3 : 2;
        // preload scores for all this wave's classes (independent ds_reads)
        float ps0[3], ps1[3];
        for (int k = 0; k < ncl; ++k) {
            const int lc = wv + 4 * k;
            ps0[k] = scTh[lc * kN + lane];
            ps1[k] = (lane < kN - 64) ? scTh[lc * kN + 64 + lane] : 0.f;
        }
        for (int k = 0; k < ncl; ++k) {
            const int lc = wv + 4 * k;
            const float s0 = ps0[k];
            const float s1 = ps1[k];
            const bool  c0 = (s0 >= kScoreT);
            const bool  c1 = (lane < kN - 64) && (s1 >= kScoreT);
            const unsigned long long candLo = __ballot(c0);
            const unsigned long long candHi = __ballot(c1);
            const int K = __popcll(candLo) + __popcll(candHi);

            // contested = candidate overlapping another candidate (cand ⊆ union ⇒ rows valid)
            const bool t0 = c0 && ((((rowLoA & candLo) & ~selfA) | (rowHiA & candHi)) != 0ull);
            const bool t1 = c1 && (((rowLoB & candLo) | ((rowHiB & candHi) & ~selfA)) != 0ull);
            const unsigned long long conLo = __ballot(t0);
            const unsigned long long conHi = __ballot(t1);

            unsigned long long keepLo, keepHi;
            if ((conLo | conHi) == 0ull) {
                keepLo = candLo; keepHi = candHi;          // nothing can suppress
            } else if (K <= 64) {
                // rank + scan over the contested set S only (KS <= 64)
                const int KS0 = __popcll(conLo);
                const int KS  = KS0 + __popcll(conHi);
                int q0 = 0, q1 = 0;
                if (t0) { q0 = __popcll(conLo & lt);       csc[wv][q0] = s0; cid[wv][q0] = (unsigned short)lane; }
                if (t1) { q1 = KS0 + __popcll(conHi & lt); csc[wv][q1] = s1; cid[wv][q1] = (unsigned short)(lane + 64); }
                __builtin_amdgcn_wave_barrier();
                const bool  act = (lane < KS);
                const float sp  = act ? csc[wv][lane] : 0.f;
                int rp = 0;
                for (int q = 0; q < KS; ++q) {
                    const float sq = csc[wv][q];           // broadcast read
                    rp += ((sq > sp) || ((sq == sp) && (q < lane))) ? 1 : 0;
                }
                if (act) { rnk[wv][lane] = (unsigned short)rp; rid[wv][rp] = cid[wv][lane]; }
                __builtin_amdgcn_wave_barrier();
                const int myb = act ? (int)rid[wv][lane] : 0;
                const unsigned long long rLo = adjLo[myb];
                const unsigned long long rHi = adjHi[myb];
                unsigned long long supLo = 0, supHi = 0, keepM = 0;
                for (int r = 0; r < KS; ++r) {
                    const int bi = __shfl(myb, r);         // indep of sup chain
                    const unsigned long long qLo = shfl64(rLo, r);
                    const unsigned long long qHi = shfl64(rHi, r);
                    const unsigned long long word = (bi & 64) ? supHi : supLo;
                    const unsigned long long bit  = (word >> (bi & 63)) & 1ull;
                    const unsigned long long take = bit - 1ull;  // ~0 if alive
                    keepM |= (1ull << r) & take;
                    supLo |= qLo & take;
                    supHi |= qHi & take;
                }
                const bool k0 = t0 && ((keepM >> rnk[wv][q0]) & 1ull);
                const bool k1 = t1 && ((keepM >> rnk[wv][q1]) & 1ull);
                keepLo = (candLo & ~conLo) | __ballot(k0);
                keepHi = (candHi & ~conHi) | __ballot(k1);
            } else {
                // fallback (K>64, prob ~0): ballot-greedy over all candidates
                const int K0 = __popcll(candLo);
                int p0 = 0, p1 = 0;
                if (c0) { p0 = __popcll(candLo & lt);      csc[wv][p0] = s0; cid[wv][p0] = (unsigned short)lane; }
                if (c1) { p1 = K0 + __popcll(candHi & lt); csc[wv][p1] = s1; cid[wv][p1] = (unsigned short)(lane + 64); }
                __builtin_amdgcn_wave_barrier();
                bool al0 = c0, al1 = c1, k0 = false, k1 = false;
                const float n0x1 = x1s[lane], n0y1 = y1s[lane], n0x2 = x2s[lane], n0y2 = y2s[lane];
                const float n1x1 = x1s[nB],  n1y1 = y1s[nB],  n1x2 = x2s[nB],  n1y2 = y2s[nB];
                for (;;) {
                    float bs; int bp;
                    if (al0 && (!al1 || s0 >= s1)) { bs = s0; bp = p0; }
                    else if (al1)                  { bs = s1; bp = p1; }
                    else                           { bs = -1e30f; bp = 1 << 20; }
                    for (int off = 32; off; off >>= 1) {
                        const float os = __shfl_xor(bs, off);
                        const int   op = __shfl_xor(bp, off);
                        if (os > bs || (os == bs && op < bp)) { bs = os; bp = op; }
                    }
                    if (bp >= (1 << 20)) break;
                    const int bi = cid[wv][bp];            // wave-uniform
                    const float kx1 = x1s[bi], ky1 = y1s[bi], kx2 = x2s[bi], ky2 = y2s[bi];
                    if (bp == p0 && al0) { k0 = true; al0 = false; }
                    if (bp == p1 && al1) { k1 = true; al1 = false; }
                    if (al0 && iou_f(kx1, ky1, kx2, ky2, n0x1, n0y1, n0x2, n0y2) > kIouT) al0 = false;
                    if (al1 && iou_f(kx1, ky1, kx2, ky2, n1x1, n1y1, n1x2, n1y2) > kIouT) al1 = false;
                }
                keepLo = __ballot(k0);
                keepHi = __ballot(k1);
            }
            if (lane == 0) {
                km[lc][0] = (unsigned)keepLo;
                km[lc][1] = (unsigned)(keepLo >> 32);
                km[lc][2] = (unsigned)keepHi;
                km[lc][3] = (unsigned)(keepHi >> 32);
            }
        }
    }
    __syncthreads();

    // ---- phase 4: writer — our half's 490 row-pairs (c0i,c1i in [10h,10h+10)) ----
    for (int t = tid; t < (kRows / 2) / 2; t += kT) {     // 490 pairs
        const int n   = t / 5;
        const int q   = 5 * h + t % 5;                    // row-pair slot in [5h,5h+5)
        const int lc0 = 2 * (t % 5);                      // local even class
        const int c0i = kHC * h + lc0;                    // global class ids
        const int c1i = c0i + 1;
        const float sA = scTh[lc0 * kN + n];
        const float sB = scTh[(lc0 + 1) * kN + n];
        const float bbx = x1s[n], bby = y1s[n], bbz = x2s[n], bbw = y2s[n];
        const float mA = ((km[lc0][n >> 5] >> (n & 31)) & 1u) ? 1.f : 0.f;
        const float mB = ((km[lc0 + 1][n >> 5] >> (n & 31)) & 1u) ? 1.f : 0.f;
        float* ob = out + (size_t)b * kOutF + (size_t)12 * (n * 10 + q);
        float4 q0, q1, q2;
        q0.x = mA * (float)c0i; q0.y = mA * bbx; q0.z = mA * bby; q0.w = mA * bbz;
        q1.x = mA * bbw;        q1.y = mA * sA;  q1.z = mB * (float)c1i; q1.w = mB * bbx;
        q2.x = mB * bby;        q2.y = mB * bbz; q2.z = mB * bbw;        q2.w = mB * sB;
        reinterpret_cast<float4*>(ob)[0] = q0;
        reinterpret_cast<float4*>(ob)[1] = q1;
        reinterpret_cast<float4*>(ob)[2] = q2;
    }
}

extern "C" void kernel_launch(void* const* d_in, const int* in_sizes, int n_in,
                              void* d_out, int out_size, void* d_ws, size_t ws_size,
                              hipStream_t stream) {
    const float* x = (const float*)d_in[0];
    float* out = (float*)d_out;
    const int B = in_sizes[0] / (kS * kS * kFeat);   // 1024
    hipLaunchKernelGGL(yolo_head_kernel, dim3(2 * B), dim3(kT), 0, stream, x, out);
}

// Round 12
// 90.003 us; speedup vs baseline: 1.3605x; 1.1429x over previous
//
#include <hip/hip_runtime.h>

// YOLOv1 head post-process — R12: R9 structure (256thr, grid=B, 16 waves/CU —
// measured sweet spot: R10 showed <16 waves/CU is latency-bound, R11 showed
// >16 with duplicated prep costs linearly => we are instruction-throughput
// bound). This round deletes instructions:
//  1) output write FUSED into the NMS class loop (per-lane k0/k1/s0/s1/boxes
//     already in registers; 3x float2 per row, per-class immediate offsets).
//     Phase-4 writer, its barrier, km[] and all its LDS re-reads: gone.
//  2) division-free EXACT IoU test: RN(inter/udiv) > 0.5  <=>
//     (double)inter > (double)udiv*(0.5+2^-25)  (product exact: 24+25<=53
//     bits; tie at the midpoint rounds-to-even to 0.5 => excluded by strict >,
//     matching the reference float divide bit-for-bit).
//  3) rank scan maps keep-bits back via a position-space ballot (rnk[] LDS
//     round-trips dropped).
// Carried equivalences (R1-R5, R8-R11 all passed):
//  * score < SCORE_T boxes only suppress even-lower-sorted boxes (all zeroed
//    by final score filter) -> NMS over score>=SCORE_T candidates exact.
//  * candidate => conf*(1/sum) >= SCORE_T in float (monotone) -> union mask
//    covers every candidate; non-union adj rows are never semantically read.
//  * contested-set restriction exact (IoU symmetric): candidate overlapping
//    no other candidate is always kept; NMS(cand) = (cand\S) ∪ NMS(S).
//  * rank tie-break = box index ascending = jnp stable argsort(-scores).
//  * K>64 (prob ~0) falls back to ballot-greedy (exact).
// Softmax float-op sequence bit-identical to R1-R11.

namespace {
constexpr int kS    = 7;
constexpr int kC    = 20;
constexpr int kFeat = 30;             // C + 5*BBOX
constexpr int kN    = 98;             // S*S*2 boxes
constexpr int kRows = kN * kC;        // 1960
constexpr int kOutF = kRows * 6;      // 11760 floats per batch
constexpr int kT    = 256;            // threads per block (4 waves)
constexpr float kScoreT = 0.05f;
// RN32(inter/udiv) > 0.5  <=>  inter > udiv*(0.5+2^-25) in exact arithmetic
constexpr double kIouCmp = 0.50000001490116119384765625;   // 0.5 + 2^-25
}

// exact threshold test for reference's  inter/max(uni,1e-9) > 0.5
__device__ __forceinline__ bool iou_gt(float ax1, float ay1, float ax2, float ay2,
                                       float bx1, float by1, float bx2, float by2) {
#pragma clang fp contract(off)
    float aa = fmaxf(ax2 - ax1, 0.f) * fmaxf(ay2 - ay1, 0.f);
    float ab = fmaxf(bx2 - bx1, 0.f) * fmaxf(by2 - by1, 0.f);
    float ix1 = fmaxf(ax1, bx1);
    float iy1 = fmaxf(ay1, by1);
    float ix2 = fminf(ax2, bx2);
    float iy2 = fminf(ay2, by2);
    float inter = fmaxf(ix2 - ix1, 0.f) * fmaxf(iy2 - iy1, 0.f);
    float udiv = fmaxf(aa + ab - inter, 1e-9f);
    return (double)inter > (double)udiv * kIouCmp;
}

__device__ __forceinline__ unsigned long long shfl64(unsigned long long v, int src) {
    unsigned lo = (unsigned)__shfl((int)(unsigned)(v & 0xffffffffull), src);
    unsigned hi = (unsigned)__shfl((int)(unsigned)(v >> 32), src);
    return ((unsigned long long)hi << 32) | lo;
}

__global__ __launch_bounds__(kT, 4) void yolo_head_kernel(const float* __restrict__ x,
                                                          float* __restrict__ out) {
    __shared__ float xs[kS * kS * kFeat];                   // 1470 input floats
    __shared__ float scT[kRows];                            // scores [c][n]
    __shared__ float maxp[kS * kS];                         // 1/sum per cell
    __shared__ float x1s[kN], y1s[kN], x2s[kN], y2s[kN];    // SoA boxes
    __shared__ unsigned long long adjLo[kN], adjHi[kN];     // IoU>T rows (union only)
    __shared__ float csc[4][kN];                            // per-wave cand scores
    __shared__ unsigned short cid[4][kN];                   // per-wave cand box idx
    __shared__ unsigned short rid[4][64];                   // rank -> box idx

    const int b   = blockIdx.x;
    const int tid = threadIdx.x;
    const float* xb = x + (size_t)b * (kS * kS * kFeat);

    for (int e = tid; e < (kS * kS * kFeat) / 2; e += kT)
        reinterpret_cast<float2*>(xs)[e] = reinterpret_cast<const float2*>(xb)[e];
    __syncthreads();

    // ---- phase 1: softmax (threads 0-48, bit-identical op order) + decode (64-161) ----
    if (tid < kS * kS) {
#pragma clang fp contract(off)
        const int cell = tid;
        const float* p = &xs[cell * kFeat];
        float mx = p[0];
        for (int c = 1; c < kC; ++c) mx = fmaxf(mx, p[c]);
        float e[kC];
        float sum = 0.f;
        for (int c = 0; c < kC; ++c) { e[c] = expf(p[c] - mx); sum += e[c]; }
        const float conf0 = p[28], conf1 = p[29];
        for (int c = 0; c < kC; ++c) {
            float pr = e[c] / sum;
            scT[c * kN + 2 * cell]     = pr * conf0;
            scT[c * kN + 2 * cell + 1] = pr * conf1;
        }
        maxp[cell] = 1.0f / sum;    // exp(0)=1 is the exact max of e[]
    } else if (tid >= 64 && tid < 64 + kN) {
#pragma clang fp contract(off)
        const int n = tid - 64;
        const int cell = n >> 1, k = n & 1;
        const int gi = cell / kS, gj = cell % kS;   // gy=gi, gx=gj
        const float* p = &xs[cell * kFeat + kC + 4 * k];
        float cx = (p[0] + (float)gj) / 7.0f;
        float cy = (p[1] + (float)gi) / 7.0f;
        float w = p[2], h2 = p[3];
        x1s[n] = fminf(fmaxf(cx - w * 0.5f, 0.f), 1.f) * 448.f;
        y1s[n] = fminf(fmaxf(cy - h2 * 0.5f, 0.f), 1.f) * 448.f;
        x2s[n] = fminf(fmaxf(cx + w * 0.5f, 0.f), 1.f) * 448.f;
        y2s[n] = fminf(fmaxf(cy + h2 * 0.5f, 0.f), 1.f) * 448.f;
    }
    __syncthreads();

    const int wv   = tid >> 6;
    const int lane = tid & 63;
    const bool hasB = (lane < kN - 64);
    const int nB   = hasB ? lane + 64 : 0;               // valid dummy for lane>=34

    // per-lane box coords in registers (used by adjacency, fallback, and writes)
    const float aX1 = x1s[lane], aY1 = y1s[lane], aX2 = x2s[lane], aY2 = y2s[lane];
    const float bX1 = x1s[nB],  bY1 = y1s[nB],  bX2 = x2s[nB],  bY2 = y2s[nB];

    // ---- phase 2: union mask + ballot-built adjacency (wave wv: rows wv, wv+4, ...) ----
    {
        const int cA = lane >> 1, kA = lane & 1;
        const bool uA = xs[cA * kFeat + 28 + kA] * maxp[cA] >= kScoreT;
        bool uB = false;
        if (hasB) {
            const int cB = nB >> 1, kB = nB & 1;
            uB = xs[cB * kFeat + 28 + kB] * maxp[cB] >= kScoreT;
        }
        const unsigned long long ULo = __ballot(uA);
        const unsigned long long UHi = __ballot(uB);
        for (int i = wv; i < kN; i += 4) {
            const bool inU = (i < 64) ? ((ULo >> i) & 1ull) : ((UHi >> (i - 64)) & 1ull);
            if (!inU) continue;
            const float iX1 = x1s[i], iY1 = y1s[i], iX2 = x2s[i], iY2 = y2s[i];
            const bool oA = iou_gt(iX1, iY1, iX2, iY2, aX1, aY1, aX2, aY2);
            const bool oB = hasB && iou_gt(iX1, iY1, iX2, iY2, bX1, bY1, bX2, bY2);
            const unsigned long long rLo = __ballot(oA);
            const unsigned long long rHi = __ballot(oB);
            if (lane == 0) { adjLo[i] = rLo; adjHi[i] = rHi; }
        }
    }
    __syncthreads();

    // ---- phase 3: per-class NMS (contested-set) with FUSED output write ----
    {
        const unsigned long long rowLoA = adjLo[lane], rowHiA = adjHi[lane];
        const unsigned long long rowLoB = adjLo[nB],   rowHiB = adjHi[nB];
        const unsigned long long selfA  = 1ull << lane;  // A self in Lo; B self in Hi bit `lane`
        const unsigned long long lt     = (1ull << lane) - 1ull;
        float* const obA = out + (size_t)b * kOutF + (size_t)lane * (kC * 6);
        float* const obB = obA + 64 * (kC * 6);          // row base for box lane+64

        for (int pass = 0; pass < 5; ++pass) {
            const int c = wv + 4 * pass;                 // always < 20

            const float s0 = scT[c * kN + lane];
            const float s1 = hasB ? scT[c * kN + 64 + lane] : 0.f;
            const bool  c0 = (s0 >= kScoreT);
            const bool  c1 = hasB && (s1 >= kScoreT);
            const unsigned long long candLo = __ballot(c0);
            const unsigned long long candHi = __ballot(c1);
            const int K = __popcll(candLo) + __popcll(candHi);

            // contested = candidate overlapping another candidate (cand ⊆ union ⇒ rows valid)
            const bool t0 = c0 && ((((rowLoA & candLo) & ~selfA) | (rowHiA & candHi)) != 0ull);
            const bool t1 = c1 && (((rowLoB & candLo) | ((rowHiB & candHi) & ~selfA)) != 0ull);
            const unsigned long long conLo = __ballot(t0);
            const unsigned long long conHi = __ballot(t1);

            bool k0, k1;
            if ((conLo | conHi) == 0ull) {
                k0 = c0; k1 = c1;                        // nothing can suppress
            } else if (K <= 64) {
                // rank + scan over the contested set S only (KS <= 64)
                const int KS0 = __popcll(conLo);
                const int KS  = KS0 + __popcll(conHi);
                int q0 = 0, q1 = 0;
                if (t0) { q0 = __popcll(conLo & lt);       csc[wv][q0] = s0; cid[wv][q0] = (unsigned short)lane; }
                if (t1) { q1 = KS0 + __popcll(conHi & lt); csc[wv][q1] = s1; cid[wv][q1] = (unsigned short)(lane + 64); }
                __builtin_amdgcn_wave_barrier();
                const bool  act = (lane < KS);
                const float sp  = act ? csc[wv][lane] : 0.f;
                int rp = 0;
                for (int q = 0; q < KS; ++q) {
                    const float sq = csc[wv][q];           // broadcast read
                    rp += ((sq > sp) || ((sq == sp) && (q < lane))) ? 1 : 0;
                }
                if (act) rid[wv][rp] = cid[wv][lane];
                __builtin_amdgcn_wave_barrier();
                const int myb = act ? (int)rid[wv][lane] : 0;
                const unsigned long long rLo = adjLo[myb];
                const unsigned long long rHi = adjHi[myb];
                unsigned long long supLo = 0, supHi = 0, keepM = 0;
                for (int r = 0; r < KS; ++r) {
                    const int bi = __shfl(myb, r);         // indep of sup chain
                    const unsigned long long qLo = shfl64(rLo, r);
                    const unsigned long long qHi = shfl64(rHi, r);
                    const unsigned long long word = (bi & 64) ? supHi : supLo;
                    const unsigned long long bit  = (word >> (bi & 63)) & 1ull;
                    const unsigned long long take = bit - 1ull;  // ~0 if alive
                    keepM |= (1ull << r) & take;
                    supLo |= qLo & take;
                    supHi |= qHi & take;
                }
                // keep-bit of contested position `lane` is keepM bit rp ->
                // broadcast to position space with one ballot
                const unsigned long long posKeep = __ballot(act && ((keepM >> rp) & 1ull));
                k0 = c0 && (!t0 || ((posKeep >> q0) & 1ull));
                k1 = c1 && (!t1 || ((posKeep >> q1) & 1ull));
            } else {
                // fallback (K>64, prob ~0): ballot-greedy over all candidates
                const int K0 = __popcll(candLo);
                int p0 = 0, p1 = 0;
                if (c0) { p0 = __popcll(candLo & lt);      csc[wv][p0] = s0; cid[wv][p0] = (unsigned short)lane; }
                if (c1) { p1 = K0 + __popcll(candHi & lt); csc[wv][p1] = s1; cid[wv][p1] = (unsigned short)(lane + 64); }
                __builtin_amdgcn_wave_barrier();
                bool al0 = c0, al1 = c1;
                k0 = false; k1 = false;
                for (;;) {
                    float bs; int bp;
                    if (al0 && (!al1 || s0 >= s1)) { bs = s0; bp = p0; }
                    else if (al1)                  { bs = s1; bp = p1; }
                    else                           { bs = -1e30f; bp = 1 << 20; }
                    for (int off = 32; off; off >>= 1) {
                        const float os = __shfl_xor(bs, off);
                        const int   op = __shfl_xor(bp, off);
                        if (os > bs || (os == bs && op < bp)) { bs = os; bp = op; }
                    }
                    if (bp >= (1 << 20)) break;
                    const int bi = cid[wv][bp];            // wave-uniform
                    const float kx1 = x1s[bi], ky1 = y1s[bi], kx2 = x2s[bi], ky2 = y2s[bi];
                    if (bp == p0 && al0) { k0 = true; al0 = false; }
                    if (bp == p1 && al1) { k1 = true; al1 = false; }
                    if (al0 && iou_gt(kx1, ky1, kx2, ky2, aX1, aY1, aX2, aY2)) al0 = false;
                    if (al1 && iou_gt(kx1, ky1, kx2, ky2, bX1, bY1, bX2, bY2)) al1 = false;
                }
            }

            // ---- fused write: rows (lane*20+c) and ((lane+64)*20+c) ----
            {
                const float mA = k0 ? 1.f : 0.f;
                float2* rA = reinterpret_cast<float2*>(obA + c * 6);
                rA[0] = make_float2(mA * (float)c, mA * aX1);
                rA[1] = make_float2(mA * aY1,      mA * aX2);
                rA[2] = make_float2(mA * aY2,      mA * s0);
                if (hasB) {
                    const float mB = k1 ? 1.f : 0.f;
                    float2* rB = reinterpret_cast<float2*>(obB + c * 6);
                    rB[0] = make_float2(mB * (float)c, mB * bX1);
                    rB[1] = make_float2(mB * bY1,      mB * bX2);
                    rB[2] = make_float2(mB * bY2,      mB * s1);
                }
            }
        }
    }
}

extern "C" void kernel_launch(void* const* d_in, const int* in_sizes, int n_in,
                              void* d_out, int out_size, void* d_ws, size_t ws_size,
                              hipStream_t stream) {
    const float* x = (const float*)d_in[0];
    float* out = (float*)d_out;
    const int B = in_sizes[0] / (kS * kS * kFeat);   // 1024
    hipLaunchKernelGGL(yolo_head_kernel, dim3(B), dim3(kT), 0, stream, x, out);
}

// Round 13
// 82.729 us; speedup vs baseline: 1.4801x; 1.0879x over previous
//
#include <hip/hip_runtime.h>

// YOLOv1 head post-process — R13: unbundle R12. R12's fused per-class write
// (480B lane stride, 8B partial-line scatters) regressed the kernel 27->34us,
// burying its real wins. Keep the wins, revert the writer:
//  * R9 dense phase-4 writer restored (thread j -> contiguous rows 2j,2j+1,
//    48B/thread, fully coalesced float4; km[] back).
//  * division-free EXACT IoU kept: RN(inter/udiv) > 0.5 <=>
//    (double)inter > (double)udiv*(0.5+2^-25) (product exact 24+25<=53 bits;
//    midpoint ties round-to-even to 0.5, excluded by > — bit-identical).
//  * rnk-free keep mapping kept (position-space ballot).
//  * phase-2 walks only set union bits (ctz, round-robin over 4 waves).
// Structure: 256 thr, grid=B, 16 waves/CU (R10: fewer => latency-bound;
// R11: more w/ duplicated prep => linear cost; we are throughput-bound here).
// Carried equivalences (R1-R5, R8-R12 all passed):
//  * score < SCORE_T boxes only suppress even-lower-sorted boxes (all zeroed
//    by final score filter) -> NMS over score>=SCORE_T candidates exact.
//  * candidate => conf*(1/sum) >= SCORE_T in float (monotone) -> union mask
//    covers every candidate; non-union adj rows never semantically read.
//  * contested-set restriction exact (IoU symmetric).
//  * rank tie-break = box index ascending = jnp stable argsort(-scores).
//  * K>64 (prob ~0) falls back to ballot-greedy (exact).
// Softmax float-op sequence bit-identical to R1-R12.

namespace {
constexpr int kS    = 7;
constexpr int kC    = 20;
constexpr int kFeat = 30;             // C + 5*BBOX
constexpr int kN    = 98;             // S*S*2 boxes
constexpr int kRows = kN * kC;        // 1960
constexpr int kOutF = kRows * 6;      // 11760 floats per batch
constexpr int kT    = 256;            // threads per block (4 waves)
constexpr float kScoreT = 0.05f;
constexpr double kIouCmp = 0.50000001490116119384765625;   // 0.5 + 2^-25
}

// exact threshold test for reference's  inter/max(uni,1e-9) > 0.5
__device__ __forceinline__ bool iou_gt(float ax1, float ay1, float ax2, float ay2,
                                       float bx1, float by1, float bx2, float by2) {
#pragma clang fp contract(off)
    float aa = fmaxf(ax2 - ax1, 0.f) * fmaxf(ay2 - ay1, 0.f);
    float ab = fmaxf(bx2 - bx1, 0.f) * fmaxf(by2 - by1, 0.f);
    float ix1 = fmaxf(ax1, bx1);
    float iy1 = fmaxf(ay1, by1);
    float ix2 = fminf(ax2, bx2);
    float iy2 = fminf(ay2, by2);
    float inter = fmaxf(ix2 - ix1, 0.f) * fmaxf(iy2 - iy1, 0.f);
    float udiv = fmaxf(aa + ab - inter, 1e-9f);
    return (double)inter > (double)udiv * kIouCmp;
}

__device__ __forceinline__ unsigned long long shfl64(unsigned long long v, int src) {
    unsigned lo = (unsigned)__shfl((int)(unsigned)(v & 0xffffffffull), src);
    unsigned hi = (unsigned)__shfl((int)(unsigned)(v >> 32), src);
    return ((unsigned long long)hi << 32) | lo;
}

__global__ __launch_bounds__(kT, 4) void yolo_head_kernel(const float* __restrict__ x,
                                                          float* __restrict__ out) {
    __shared__ float xs[kS * kS * kFeat];                   // 1470 input floats
    __shared__ float scT[kRows];                            // scores [c][n]
    __shared__ float maxp[kS * kS];                         // 1/sum per cell
    __shared__ float x1s[kN], y1s[kN], x2s[kN], y2s[kN];    // SoA boxes
    __shared__ unsigned long long adjLo[kN], adjHi[kN];     // IoU>T rows (union only)
    __shared__ float csc[4][kN];                            // per-wave cand scores
    __shared__ unsigned short cid[4][kN];                   // per-wave cand box idx
    __shared__ unsigned short rid[4][64];                   // rank -> box idx
    __shared__ unsigned km[kC][4];                          // keep mask per class

    const int b   = blockIdx.x;
    const int tid = threadIdx.x;
    const float* xb = x + (size_t)b * (kS * kS * kFeat);

    for (int e = tid; e < (kS * kS * kFeat) / 2; e += kT)
        reinterpret_cast<float2*>(xs)[e] = reinterpret_cast<const float2*>(xb)[e];
    __syncthreads();

    // ---- phase 1: softmax (threads 0-48, bit-identical op order) + decode (64-161) ----
    if (tid < kS * kS) {
#pragma clang fp contract(off)
        const int cell = tid;
        const float* p = &xs[cell * kFeat];
        float mx = p[0];
        for (int c = 1; c < kC; ++c) mx = fmaxf(mx, p[c]);
        float e[kC];
        float sum = 0.f;
        for (int c = 0; c < kC; ++c) { e[c] = expf(p[c] - mx); sum += e[c]; }
        const float conf0 = p[28], conf1 = p[29];
        for (int c = 0; c < kC; ++c) {
            float pr = e[c] / sum;
            scT[c * kN + 2 * cell]     = pr * conf0;
            scT[c * kN + 2 * cell + 1] = pr * conf1;
        }
        maxp[cell] = 1.0f / sum;    // exp(0)=1 is the exact max of e[]
    } else if (tid >= 64 && tid < 64 + kN) {
#pragma clang fp contract(off)
        const int n = tid - 64;
        const int cell = n >> 1, k = n & 1;
        const int gi = cell / kS, gj = cell % kS;   // gy=gi, gx=gj
        const float* p = &xs[cell * kFeat + kC + 4 * k];
        float cx = (p[0] + (float)gj) / 7.0f;
        float cy = (p[1] + (float)gi) / 7.0f;
        float w = p[2], h2 = p[3];
        x1s[n] = fminf(fmaxf(cx - w * 0.5f, 0.f), 1.f) * 448.f;
        y1s[n] = fminf(fmaxf(cy - h2 * 0.5f, 0.f), 1.f) * 448.f;
        x2s[n] = fminf(fmaxf(cx + w * 0.5f, 0.f), 1.f) * 448.f;
        y2s[n] = fminf(fmaxf(cy + h2 * 0.5f, 0.f), 1.f) * 448.f;
    }
    __syncthreads();

    const int wv   = tid >> 6;
    const int lane = tid & 63;
    const bool hasB = (lane < kN - 64);
    const int nB   = hasB ? lane + 64 : 0;               // valid dummy for lane>=34

    // per-lane box coords in registers (adjacency + fallback)
    const float aX1 = x1s[lane], aY1 = y1s[lane], aX2 = x2s[lane], aY2 = y2s[lane];
    const float bX1 = x1s[nB],  bY1 = y1s[nB],  bX2 = x2s[nB],  bY2 = y2s[nB];

    // ---- phase 2: union mask + ballot adjacency (ctz walk, round-robin waves) ----
    {
        const int cA = lane >> 1, kA = lane & 1;
        const bool uA = xs[cA * kFeat + 28 + kA] * maxp[cA] >= kScoreT;
        bool uB = false;
        if (hasB) {
            const int cB = nB >> 1, kB = nB & 1;
            uB = xs[cB * kFeat + 28 + kB] * maxp[cB] >= kScoreT;
        }
        const unsigned long long ULo = __ballot(uA);
        const unsigned long long UHi = __ballot(uB);
        int idx = 0;
        unsigned long long m = ULo;
        while (m) {
            const int i = __builtin_ctzll(m);
            m &= m - 1;
            if ((idx++ & 3) != wv) continue;            // round-robin over waves
            const float iX1 = x1s[i], iY1 = y1s[i], iX2 = x2s[i], iY2 = y2s[i];
            const bool oA = iou_gt(iX1, iY1, iX2, iY2, aX1, aY1, aX2, aY2);
            const bool oB = hasB && iou_gt(iX1, iY1, iX2, iY2, bX1, bY1, bX2, bY2);
            const unsigned long long rLo = __ballot(oA);
            const unsigned long long rHi = __ballot(oB);
            if (lane == 0) { adjLo[i] = rLo; adjHi[i] = rHi; }
        }
        m = UHi;
        while (m) {
            const int i = 64 + __builtin_ctzll(m);
            m &= (m - 1) & 0xffffffffffffffffull;
            m &= m; // no-op clarity
            if ((idx++ & 3) != wv) continue;
            const float iX1 = x1s[i], iY1 = y1s[i], iX2 = x2s[i], iY2 = y2s[i];
            const bool oA = iou_gt(iX1, iY1, iX2, iY2, aX1, aY1, aX2, aY2);
            const bool oB = hasB && iou_gt(iX1, iY1, iX2, iY2, bX1, bY1, bX2, bY2);
            const unsigned long long rLo = __ballot(oA);
            const unsigned long long rHi = __ballot(oB);
            if (lane == 0) { adjLo[i] = rLo; adjHi[i] = rHi; }
        }
    }
    __syncthreads();

    // ---- phase 3: per-class NMS with contested-set restriction (5 classes/wave) ----
    {
        const unsigned long long rowLoA = adjLo[lane], rowHiA = adjHi[lane];
        const unsigned long long rowLoB = adjLo[nB],   rowHiB = adjHi[nB];
        const unsigned long long selfA  = 1ull << lane;  // A self in Lo; B self in Hi bit `lane`
        const unsigned long long lt     = (1ull << lane) - 1ull;
        for (int pass = 0; pass < 5; ++pass) {
            const int c = wv + 4 * pass;                 // always < 20

            const float s0 = scT[c * kN + lane];
            const float s1 = hasB ? scT[c * kN + 64 + lane] : 0.f;
            const bool  c0 = (s0 >= kScoreT);
            const bool  c1 = hasB && (s1 >= kScoreT);
            const unsigned long long candLo = __ballot(c0);
            const unsigned long long candHi = __ballot(c1);
            const int K = __popcll(candLo) + __popcll(candHi);

            // contested = candidate overlapping another candidate
            const bool t0 = c0 && ((((rowLoA & candLo) & ~selfA) | (rowHiA & candHi)) != 0ull);
            const bool t1 = c1 && (((rowLoB & candLo) | ((rowHiB & candHi) & ~selfA)) != 0ull);
            const unsigned long long conLo = __ballot(t0);
            const unsigned long long conHi = __ballot(t1);

            unsigned long long keepLo, keepHi;
            if ((conLo | conHi) == 0ull) {
                keepLo = candLo; keepHi = candHi;        // nothing can suppress
            } else if (K <= 64) {
                // rank + scan over the contested set S only (KS <= 64)
                const int KS0 = __popcll(conLo);
                const int KS  = KS0 + __popcll(conHi);
                int q0 = 0, q1 = 0;
                if (t0) { q0 = __popcll(conLo & lt);       csc[wv][q0] = s0; cid[wv][q0] = (unsigned short)lane; }
                if (t1) { q1 = KS0 + __popcll(conHi & lt); csc[wv][q1] = s1; cid[wv][q1] = (unsigned short)(lane + 64); }
                __builtin_amdgcn_wave_barrier();
                const bool  act = (lane < KS);
                const float sp  = act ? csc[wv][lane] : 0.f;
                int rp = 0;
                for (int q = 0; q < KS; ++q) {
                    const float sq = csc[wv][q];           // broadcast read
                    rp += ((sq > sp) || ((sq == sp) && (q < lane))) ? 1 : 0;
                }
                if (act) rid[wv][rp] = cid[wv][lane];
                __builtin_amdgcn_wave_barrier();
                const int myb = act ? (int)rid[wv][lane] : 0;
                const unsigned long long rLo = adjLo[myb];
                const unsigned long long rHi = adjHi[myb];
                unsigned long long supLo = 0, supHi = 0, keepM = 0;
                for (int r = 0; r < KS; ++r) {
                    const int bi = __shfl(myb, r);         // indep of sup chain
                    const unsigned long long qLo = shfl64(rLo, r);
                    const unsigned long long qHi = shfl64(rHi, r);
                    const unsigned long long word = (bi & 64) ? supHi : supLo;
                    const unsigned long long bit  = (word >> (bi & 63)) & 1ull;
                    const unsigned long long take = bit - 1ull;  // ~0 if alive
                    keepM |= (1ull << r) & take;
                    supLo |= qLo & take;
                    supHi |= qHi & take;
                }
                // keep-bit of contested position `lane` = keepM bit rp ->
                // broadcast back to position space with one ballot
                const unsigned long long posKeep = __ballot(act && ((keepM >> rp) & 1ull));
                const bool k0 = t0 && ((posKeep >> q0) & 1ull);
                const bool k1 = t1 && ((posKeep >> q1) & 1ull);
                keepLo = (candLo & ~conLo) | __ballot(k0);
                keepHi = (candHi & ~conHi) | __ballot(k1);
            } else {
                // fallback (K>64, prob ~0): ballot-greedy over all candidates
                const int K0 = __popcll(candLo);
                int p0 = 0, p1 = 0;
                if (c0) { p0 = __popcll(candLo & lt);      csc[wv][p0] = s0; cid[wv][p0] = (unsigned short)lane; }
                if (c1) { p1 = K0 + __popcll(candHi & lt); csc[wv][p1] = s1; cid[wv][p1] = (unsigned short)(lane + 64); }
                __builtin_amdgcn_wave_barrier();
                bool al0 = c0, al1 = c1, k0 = false, k1 = false;
                for (;;) {
                    float bs; int bp;
                    if (al0 && (!al1 || s0 >= s1)) { bs = s0; bp = p0; }
                    else if (al1)                  { bs = s1; bp = p1; }
                    else                           { bs = -1e30f; bp = 1 << 20; }
                    for (int off = 32; off; off >>= 1) {
                        const float os = __shfl_xor(bs, off);
                        const int   op = __shfl_xor(bp, off);
                        if (os > bs || (os == bs && op < bp)) { bs = os; bp = op; }
                    }
                    if (bp >= (1 << 20)) break;
                    const int bi = cid[wv][bp];            // wave-uniform
                    const float kx1 = x1s[bi], ky1 = y1s[bi], kx2 = x2s[bi], ky2 = y2s[bi];
                    if (bp == p0 && al0) { k0 = true; al0 = false; }
                    if (bp == p1 && al1) { k1 = true; al1 = false; }
                    if (al0 && iou_gt(kx1, ky1, kx2, ky2, aX1, aY1, aX2, aY2)) al0 = false;
                    if (al1 && iou_gt(kx1, ky1, kx2, ky2, bX1, bY1, bX2, bY2)) al1 = false;
                }
                keepLo = __ballot(k0);
                keepHi = __ballot(k1);
            }
            if (lane == 0) {
                km[c][0] = (unsigned)keepLo;
                km[c][1] = (unsigned)(keepLo >> 32);
                km[c][2] = (unsigned)keepHi;
                km[c][3] = (unsigned)(keepHi >> 32);
            }
        }
    }
    __syncthreads();

    // ---- phase 4: dense coalesced writer — thread j emits rows 2j,2j+1 ----
    for (int j = tid; j < kRows / 2; j += kT) {
        const int n = j / 10;                 // rows 2j,2j+1 share n
        const int c0i = 2 * (j % 10);
        const int c1i = c0i + 1;
        const float sA = scT[c0i * kN + n];
        const float sB = scT[c1i * kN + n];
        const float bbx = x1s[n], bby = y1s[n], bbz = x2s[n], bbw = y2s[n];
        const float mA = ((km[c0i][n >> 5] >> (n & 31)) & 1u) ? 1.f : 0.f;
        const float mB = ((km[c1i][n >> 5] >> (n & 31)) & 1u) ? 1.f : 0.f;
        float* ob = out + (size_t)b * kOutF + (size_t)12 * j;
        float4 q0, q1, q2;
        q0.x = mA * (float)c0i; q0.y = mA * bbx; q0.z = mA * bby; q0.w = mA * bbz;
        q1.x = mA * bbw;        q1.y = mA * sA;  q1.z = mB * (float)c1i; q1.w = mB * bbx;
        q2.x = mB * bby;        q2.y = mB * bbz; q2.z = mB * bbw;        q2.w = mB * sB;
        reinterpret_cast<float4*>(ob)[0] = q0;
        reinterpret_cast<float4*>(ob)[1] = q1;
        reinterpret_cast<float4*>(ob)[2] = q2;
    }
}

extern "C" void kernel_launch(void* const* d_in, const int* in_sizes, int n_in,
                              void* d_out, int out_size, void* d_ws, size_t ws_size,
                              hipStream_t stream) {
    const float* x = (const float*)d_in[0];
    float* out = (float*)d_out;
    const int B = in_sizes[0] / (kS * kS * kFeat);   // 1024
    hipLaunchKernelGGL(yolo_head_kernel, dim3(B), dim3(kT), 0, stream, x, out);
}

// Round 14
// 81.652 us; speedup vs baseline: 1.4996x; 1.0132x over previous
//
#include <hip/hip_runtime.h>

// YOLOv1 head post-process — R14: R13 minus LDS-pipe traffic. Measured state:
// 16 waves/CU, VALU ~28% busy, kernel ~26us => LDS issue + barrier drains are
// the residual. Cuts (no structural change):
//  1) xs[] staging deleted — softmax (floats 0-19,28-29) and decode (20-27)
//     read DISJOINT global slices directly; -735 ds_writes, -~1800 ds_reads,
//     -1 __syncthreads.
//  2) ubnd[98] = conf_k*(1/sum) written by softmax; phase-2 union test is one
//     ds_read + cmp (same float ops as before — bit-identical).
//  3) wave-uniform box broadcasts via v_readlane (SALU) in the adjacency row
//     walk and fallback — off the LDS pipe.
// Kept from R13 (82.7us best): dense coalesced phase-4 writer, division-free
// EXACT IoU ((double)inter > (double)udiv*(0.5+2^-25); product exact 24+25<=53
// bits, midpoint ties round-to-even excluded by >), rnk-free ballot keep map,
// contested-set NMS, ballot adjacency over union rows.
// Carried equivalences (R1-R5, R8-R13 all passed):
//  * score < SCORE_T boxes only suppress even-lower-sorted boxes (all zeroed
//    by final score filter) -> NMS over score>=SCORE_T candidates exact.
//  * candidate => conf*(1/sum) >= SCORE_T in float (monotone) -> union mask
//    covers every candidate; non-union adj rows never semantically read.
//  * contested-set restriction exact (IoU symmetric).
//  * rank tie-break = box index ascending = jnp stable argsort(-scores).
//  * K>64 (prob ~0) falls back to ballot-greedy (exact).
// Softmax float-op sequence bit-identical to R1-R13.

namespace {
constexpr int kS    = 7;
constexpr int kC    = 20;
constexpr int kFeat = 30;             // C + 5*BBOX
constexpr int kN    = 98;             // S*S*2 boxes
constexpr int kRows = kN * kC;        // 1960
constexpr int kOutF = kRows * 6;      // 11760 floats per batch
constexpr int kT    = 256;            // threads per block (4 waves)
constexpr float kScoreT = 0.05f;
constexpr double kIouCmp = 0.50000001490116119384765625;   // 0.5 + 2^-25
}

// exact threshold test for reference's  inter/max(uni,1e-9) > 0.5
__device__ __forceinline__ bool iou_gt(float ax1, float ay1, float ax2, float ay2,
                                       float bx1, float by1, float bx2, float by2) {
#pragma clang fp contract(off)
    float aa = fmaxf(ax2 - ax1, 0.f) * fmaxf(ay2 - ay1, 0.f);
    float ab = fmaxf(bx2 - bx1, 0.f) * fmaxf(by2 - by1, 0.f);
    float ix1 = fmaxf(ax1, bx1);
    float iy1 = fmaxf(ay1, by1);
    float ix2 = fminf(ax2, bx2);
    float iy2 = fminf(ay2, by2);
    float inter = fmaxf(ix2 - ix1, 0.f) * fmaxf(iy2 - iy1, 0.f);
    float udiv = fmaxf(aa + ab - inter, 1e-9f);
    return (double)inter > (double)udiv * kIouCmp;
}

__device__ __forceinline__ unsigned long long shfl64(unsigned long long v, int src) {
    unsigned lo = (unsigned)__shfl((int)(unsigned)(v & 0xffffffffull), src);
    unsigned hi = (unsigned)__shfl((int)(unsigned)(v >> 32), src);
    return ((unsigned long long)hi << 32) | lo;
}

// wave-uniform lane read on the scalar path (no LDS pipe)
__device__ __forceinline__ float readlane_f(float v, int l) {
    return __int_as_float(__builtin_amdgcn_readlane(__float_as_int(v), l));
}

__global__ __launch_bounds__(kT, 4) void yolo_head_kernel(const float* __restrict__ x,
                                                          float* __restrict__ out) {
    __shared__ float scT[kRows];                            // scores [c][n]
    __shared__ float ubnd[kN];                              // conf_k/sum per box
    __shared__ float x1s[kN], y1s[kN], x2s[kN], y2s[kN];    // SoA boxes
    __shared__ unsigned long long adjLo[kN], adjHi[kN];     // IoU>T rows (union only)
    __shared__ float csc[4][kN];                            // per-wave cand scores
    __shared__ unsigned short cid[4][kN];                   // per-wave cand box idx
    __shared__ unsigned short rid[4][64];                   // rank -> box idx
    __shared__ unsigned km[kC][4];                          // keep mask per class

    const int b   = blockIdx.x;
    const int tid = threadIdx.x;
    const float* xb = x + (size_t)b * (kS * kS * kFeat);

    // ---- phase 1: direct-from-global softmax (0-48) + box decode (64-161) ----
    if (tid < kS * kS) {
#pragma clang fp contract(off)
        const int cell = tid;
        const float* p = xb + cell * kFeat;       // reads floats 0..19, 28..29
        float mx = p[0];
        for (int c = 1; c < kC; ++c) mx = fmaxf(mx, p[c]);
        float e[kC];
        float sum = 0.f;
        for (int c = 0; c < kC; ++c) { e[c] = expf(p[c] - mx); sum += e[c]; }
        const float conf0 = p[28], conf1 = p[29];
        for (int c = 0; c < kC; ++c) {
            float pr = e[c] / sum;
            scT[c * kN + 2 * cell]     = pr * conf0;
            scT[c * kN + 2 * cell + 1] = pr * conf1;
        }
        const float mp = 1.0f / sum;              // exp(0)=1 is the exact max of e[]
        ubnd[2 * cell]     = conf0 * mp;          // same mul as old conf*maxp test
        ubnd[2 * cell + 1] = conf1 * mp;
    } else if (tid >= 64 && tid < 64 + kN) {
#pragma clang fp contract(off)
        const int n = tid - 64;
        const int cell = n >> 1, k = n & 1;
        const int gi = cell / kS, gj = cell % kS;   // gy=gi, gx=gj
        const float* p = xb + cell * kFeat + kC + 4 * k;   // reads floats 20..27
        float cx = (p[0] + (float)gj) / 7.0f;
        float cy = (p[1] + (float)gi) / 7.0f;
        float w = p[2], h2 = p[3];
        x1s[n] = fminf(fmaxf(cx - w * 0.5f, 0.f), 1.f) * 448.f;
        y1s[n] = fminf(fmaxf(cy - h2 * 0.5f, 0.f), 1.f) * 448.f;
        x2s[n] = fminf(fmaxf(cx + w * 0.5f, 0.f), 1.f) * 448.f;
        y2s[n] = fminf(fmaxf(cy + h2 * 0.5f, 0.f), 1.f) * 448.f;
    }
    __syncthreads();

    const int wv   = tid >> 6;
    const int lane = tid & 63;
    const bool hasB = (lane < kN - 64);
    const int nB   = hasB ? lane + 64 : 0;               // valid dummy for lane>=34

    // per-lane box coords in registers (stride-4B conflict-free LDS loads)
    const float aX1 = x1s[lane], aY1 = y1s[lane], aX2 = x2s[lane], aY2 = y2s[lane];
    const float bX1 = x1s[nB],  bY1 = y1s[nB],  bX2 = x2s[nB],  bY2 = y2s[nB];

    // ---- phase 2: union mask + ballot adjacency (ctz walk, round-robin waves) ----
    {
        const bool uA = ubnd[lane] >= kScoreT;
        const bool uB = hasB && (ubnd[nB] >= kScoreT);
        const unsigned long long ULo = __ballot(uA);
        const unsigned long long UHi = __ballot(uB);
        int idx = 0;
        unsigned long long m = ULo;
        while (m) {
            const int i = __builtin_ctzll(m);
            m &= m - 1;
            if ((idx++ & 3) != wv) continue;            // round-robin over waves
            const float iX1 = readlane_f(aX1, i);       // SALU broadcast, no LDS
            const float iY1 = readlane_f(aY1, i);
            const float iX2 = readlane_f(aX2, i);
            const float iY2 = readlane_f(aY2, i);
            const bool oA = iou_gt(iX1, iY1, iX2, iY2, aX1, aY1, aX2, aY2);
            const bool oB = hasB && iou_gt(iX1, iY1, iX2, iY2, bX1, bY1, bX2, bY2);
            const unsigned long long rLo = __ballot(oA);
            const unsigned long long rHi = __ballot(oB);
            if (lane == 0) { adjLo[i] = rLo; adjHi[i] = rHi; }
        }
        m = UHi;
        while (m) {
            const int j = __builtin_ctzll(m);
            m &= m - 1;
            if ((idx++ & 3) != wv) continue;
            const int i = 64 + j;
            const float iX1 = readlane_f(bX1, j);
            const float iY1 = readlane_f(bY1, j);
            const float iX2 = readlane_f(bX2, j);
            const float iY2 = readlane_f(bY2, j);
            const bool oA = iou_gt(iX1, iY1, iX2, iY2, aX1, aY1, aX2, aY2);
            const bool oB = hasB && iou_gt(iX1, iY1, iX2, iY2, bX1, bY1, bX2, bY2);
            const unsigned long long rLo = __ballot(oA);
            const unsigned long long rHi = __ballot(oB);
            if (lane == 0) { adjLo[i] = rLo; adjHi[i] = rHi; }
        }
    }
    __syncthreads();

    // ---- phase 3: per-class NMS with contested-set restriction (5 classes/wave) ----
    {
        const unsigned long long rowLoA = adjLo[lane], rowHiA = adjHi[lane];
        const unsigned long long rowLoB = adjLo[nB],   rowHiB = adjHi[nB];
        const unsigned long long selfA  = 1ull << lane;  // A self in Lo; B self in Hi bit `lane`
        const unsigned long long lt     = (1ull << lane) - 1ull;
        for (int pass = 0; pass < 5; ++pass) {
            const int c = wv + 4 * pass;                 // always < 20

            const float s0 = scT[c * kN + lane];
            const float s1 = hasB ? scT[c * kN + 64 + lane] : 0.f;
            const bool  c0 = (s0 >= kScoreT);
            const bool  c1 = hasB && (s1 >= kScoreT);
            const unsigned long long candLo = __ballot(c0);
            const unsigned long long candHi = __ballot(c1);
            const int K = __popcll(candLo) + __popcll(candHi);

            // contested = candidate overlapping another candidate
            const bool t0 = c0 && ((((rowLoA & candLo) & ~selfA) | (rowHiA & candHi)) != 0ull);
            const bool t1 = c1 && (((rowLoB & candLo) | ((rowHiB & candHi) & ~selfA)) != 0ull);
            const unsigned long long conLo = __ballot(t0);
            const unsigned long long conHi = __ballot(t1);

            unsigned long long keepLo, keepHi;
            if ((conLo | conHi) == 0ull) {
                keepLo = candLo; keepHi = candHi;        // nothing can suppress
            } else if (K <= 64) {
                // rank + scan over the contested set S only (KS <= 64)
                const int KS0 = __popcll(conLo);
                const int KS  = KS0 + __popcll(conHi);
                int q0 = 0, q1 = 0;
                if (t0) { q0 = __popcll(conLo & lt);       csc[wv][q0] = s0; cid[wv][q0] = (unsigned short)lane; }
                if (t1) { q1 = KS0 + __popcll(conHi & lt); csc[wv][q1] = s1; cid[wv][q1] = (unsigned short)(lane + 64); }
                __builtin_amdgcn_wave_barrier();
                const bool  act = (lane < KS);
                const float sp  = act ? csc[wv][lane] : 0.f;
                int rp = 0;
                for (int q = 0; q < KS; ++q) {
                    const float sq = csc[wv][q];           // broadcast read
                    rp += ((sq > sp) || ((sq == sp) && (q < lane))) ? 1 : 0;
                }
                if (act) rid[wv][rp] = cid[wv][lane];
                __builtin_amdgcn_wave_barrier();
                const int myb = act ? (int)rid[wv][lane] : 0;
                const unsigned long long rLo = adjLo[myb];
                const unsigned long long rHi = adjHi[myb];
                unsigned long long supLo = 0, supHi = 0, keepM = 0;
                for (int r = 0; r < KS; ++r) {
                    const int bi = __shfl(myb, r);         // indep of sup chain
                    const unsigned long long qLo = shfl64(rLo, r);
                    const unsigned long long qHi = shfl64(rHi, r);
                    const unsigned long long word = (bi & 64) ? supHi : supLo;
                    const unsigned long long bit  = (word >> (bi & 63)) & 1ull;
                    const unsigned long long take = bit - 1ull;  // ~0 if alive
                    keepM |= (1ull << r) & take;
                    supLo |= qLo & take;
                    supHi |= qHi & take;
                }
                // keep-bit of contested position `lane` = keepM bit rp ->
                // broadcast back to position space with one ballot
                const unsigned long long posKeep = __ballot(act && ((keepM >> rp) & 1ull));
                const bool k0 = t0 && ((posKeep >> q0) & 1ull);
                const bool k1 = t1 && ((posKeep >> q1) & 1ull);
                keepLo = (candLo & ~conLo) | __ballot(k0);
                keepHi = (candHi & ~conHi) | __ballot(k1);
            } else {
                // fallback (K>64, prob ~0): ballot-greedy over all candidates
                const int K0 = __popcll(candLo);
                int p0 = 0, p1 = 0;
                if (c0) { p0 = __popcll(candLo & lt);      csc[wv][p0] = s0; cid[wv][p0] = (unsigned short)lane; }
                if (c1) { p1 = K0 + __popcll(candHi & lt); csc[wv][p1] = s1; cid[wv][p1] = (unsigned short)(lane + 64); }
                __builtin_amdgcn_wave_barrier();
                bool al0 = c0, al1 = c1, k0 = false, k1 = false;
                for (;;) {
                    float bs; int bp;
                    if (al0 && (!al1 || s0 >= s1)) { bs = s0; bp = p0; }
                    else if (al1)                  { bs = s1; bp = p1; }
                    else                           { bs = -1e30f; bp = 1 << 20; }
                    for (int off = 32; off; off >>= 1) {
                        const float os = __shfl_xor(bs, off);
                        const int   op = __shfl_xor(bp, off);
                        if (os > bs || (os == bs && op < bp)) { bs = os; bp = op; }
                    }
                    if (bp >= (1 << 20)) break;
                    const int bi = cid[wv][bp];            // wave-uniform
                    float kx1, ky1, kx2, ky2;
                    if (bi < 64) {
                        kx1 = readlane_f(aX1, bi); ky1 = readlane_f(aY1, bi);
                        kx2 = readlane_f(aX2, bi); ky2 = readlane_f(aY2, bi);
                    } else {
                        kx1 = readlane_f(bX1, bi - 64); ky1 = readlane_f(bY1, bi - 64);
                        kx2 = readlane_f(bX2, bi - 64); ky2 = readlane_f(bY2, bi - 64);
                    }
                    if (bp == p0 && al0) { k0 = true; al0 = false; }
                    if (bp == p1 && al1) { k1 = true; al1 = false; }
                    if (al0 && iou_gt(kx1, ky1, kx2, ky2, aX1, aY1, aX2, aY2)) al0 = false;
                    if (al1 && iou_gt(kx1, ky1, kx2, ky2, bX1, bY1, bX2, bY2)) al1 = false;
                }
                keepLo = __ballot(k0);
                keepHi = __ballot(k1);
            }
            if (lane == 0) {
                km[c][0] = (unsigned)keepLo;
                km[c][1] = (unsigned)(keepLo >> 32);
                km[c][2] = (unsigned)keepHi;
                km[c][3] = (unsigned)(keepHi >> 32);
            }
        }
    }
    __syncthreads();

    // ---- phase 4: dense coalesced writer — thread j emits rows 2j,2j+1 ----
    for (int j = tid; j < kRows / 2; j += kT) {
        const int n = j / 10;                 // rows 2j,2j+1 share n
        const int c0i = 2 * (j % 10);
        const int c1i = c0i + 1;
        const float sA = scT[c0i * kN + n];
        const float sB = scT[c1i * kN + n];
        const float bbx = x1s[n], bby = y1s[n], bbz = x2s[n], bbw = y2s[n];
        const float mA = ((km[c0i][n >> 5] >> (n & 31)) & 1u) ? 1.f : 0.f;
        const float mB = ((km[c1i][n >> 5] >> (n & 31)) & 1u) ? 1.f : 0.f;
        float* ob = out + (size_t)b * kOutF + (size_t)12 * j;
        float4 q0, q1, q2;
        q0.x = mA * (float)c0i; q0.y = mA * bbx; q0.z = mA * bby; q0.w = mA * bbz;
        q1.x = mA * bbw;        q1.y = mA * sA;  q1.z = mB * (float)c1i; q1.w = mB * bbx;
        q2.x = mB * bby;        q2.y = mB * bbz; q2.z = mB * bbw;        q2.w = mB * sB;
        reinterpret_cast<float4*>(ob)[0] = q0;
        reinterpret_cast<float4*>(ob)[1] = q1;
        reinterpret_cast<float4*>(ob)[2] = q2;
    }
}

extern "C" void kernel_launch(void* const* d_in, const int* in_sizes, int n_in,
                              void* d_out, int out_size, void* d_ws, size_t ws_size,
                              hipStream_t stream) {
    const float* x = (const float*)d_in[0];
    float* out = (float*)d_out;
    const int B = in_sizes[0] / (kS * kS * kFeat);   // 1024
    hipLaunchKernelGGL(yolo_head_kernel, dim3(B), dim3(kT), 0, stream, x, out);
}